// Round 1
// baseline (1262.256 us; speedup 1.0000x reference)
//
#include <hip/hip_runtime.h>

#define N_NODES 40000
#define N_EDGES 640000
#define HD 128
#define BN_EPS 1e-5f

// ---- float <-> monotone-ordered uint mapping (for atomicMax on floats) ----
__device__ __forceinline__ unsigned fmap(float f) {
    unsigned u = __float_as_uint(f);
    return (u & 0x80000000u) ? ~u : (u | 0x80000000u);
}
__device__ __forceinline__ float funmap(unsigned u) {
    return (u & 0x80000000u) ? __uint_as_float(u ^ 0x80000000u)
                             : __uint_as_float(~u);
}

// K1: s[e] = dot(rel_emb[rel_id[e]], ent_emb[dst[e]]); atomicMax smax[dst]
__global__ __launch_bounds__(256) void k_edge_dot(
        const float* __restrict__ rel_emb, const float* __restrict__ ent_emb,
        const int* __restrict__ rel_id, const int* __restrict__ dst,
        float* __restrict__ s, unsigned* __restrict__ smax_u) {
    int t = threadIdx.x;
    int e = blockIdx.x * 8 + (t >> 5);
    if (e >= N_EDGES) return;
    int lane = t & 31;
    int r = rel_id[e], d = dst[e];
    const float4* a4 = (const float4*)(rel_emb + (size_t)r * HD);
    const float4* b4 = (const float4*)(ent_emb + (size_t)d * HD);
    float4 a = a4[lane], b = b4[lane];
    float dot = a.x * b.x + a.y * b.y + a.z * b.z + a.w * b.w;
    #pragma unroll
    for (int m = 16; m >= 1; m >>= 1) dot += __shfl_xor(dot, m, 32);
    if (lane == 0) {
        s[e] = dot;
        atomicMax(smax_u + d, fmap(dot));
    }
}

// K2: ex = exp(s - smax[dst]); denom[dst] += ex  (s overwritten with ex)
__global__ __launch_bounds__(256) void k_edge_exp(
        const int* __restrict__ dst, const unsigned* __restrict__ smax_u,
        float* __restrict__ s, float* __restrict__ denom) {
    int e = blockIdx.x * 256 + threadIdx.x;
    if (e >= N_EDGES) return;
    int d = dst[e];
    float smax = funmap(smax_u[d]);
    float ex = __expf(s[e] - smax);
    s[e] = ex;
    atomicAdd(denom + d, ex);
}

// K3: neigh[dst] += rel_emb[rel_id[e]] * (ex/denom[dst])   (atomic scatter)
__global__ __launch_bounds__(256) void k_scatter(
        const float* __restrict__ rel_emb, const int* __restrict__ rel_id,
        const int* __restrict__ dst, const float* __restrict__ ex,
        const float* __restrict__ denom, float* __restrict__ neigh) {
    int t = threadIdx.x;
    int e = blockIdx.x * 8 + (t >> 5);
    if (e >= N_EDGES) return;
    int lane = t & 31;
    int r = rel_id[e], d = dst[e];
    float norm = ex[e] / denom[d];
    const float4* a4 = (const float4*)(rel_emb + (size_t)r * HD);
    float4 a = a4[lane];
    float* out = neigh + (size_t)d * HD + lane * 4;
    atomicAdd(out + 0, a.x * norm);
    atomicAdd(out + 1, a.y * norm);
    atomicAdd(out + 2, a.z * norm);
    atomicAdd(out + 3, a.w * norm);
}

// K4: H = neigh @ W  (40000x128 @ 128x128), W staged in LDS (64 KiB)
__global__ __launch_bounds__(256) void k_gemm(
        const float* __restrict__ A, const float* __restrict__ W,
        float* __restrict__ Hout) {
    __shared__ float4 Ws4[HD * 32];
    int t = threadIdx.x;
    const float4* W4 = (const float4*)W;
    for (int i = t; i < HD * 32; i += 256) Ws4[i] = W4[i];
    __syncthreads();
    int tx = t & 31, ty = t >> 5;
    int rbase = blockIdx.x * 64 + ty * 8;
    float acc[8][4] = {};
    const float4* A4 = (const float4*)(A + (size_t)rbase * HD);
    #pragma unroll 4
    for (int k4 = 0; k4 < 32; ++k4) {
        float4 w0 = Ws4[(k4 * 4 + 0) * 32 + tx];
        float4 w1 = Ws4[(k4 * 4 + 1) * 32 + tx];
        float4 w2 = Ws4[(k4 * 4 + 2) * 32 + tx];
        float4 w3 = Ws4[(k4 * 4 + 3) * 32 + tx];
        #pragma unroll
        for (int i = 0; i < 8; ++i) {
            float4 a = A4[(size_t)i * 32 + k4];
            acc[i][0] += a.x * w0.x + a.y * w1.x + a.z * w2.x + a.w * w3.x;
            acc[i][1] += a.x * w0.y + a.y * w1.y + a.z * w2.y + a.w * w3.y;
            acc[i][2] += a.x * w0.z + a.y * w1.z + a.z * w2.z + a.w * w3.z;
            acc[i][3] += a.x * w0.w + a.y * w1.w + a.z * w2.w + a.w * w3.w;
        }
    }
    #pragma unroll
    for (int i = 0; i < 8; ++i) {
        float4 o = make_float4(acc[i][0], acc[i][1], acc[i][2], acc[i][3]);
        *(float4*)&Hout[(size_t)(rbase + i) * HD + tx * 4] = o;
    }
}

// K5: per-column sum / sumsq over rows (block-partial -> global atomics)
__global__ __launch_bounds__(256) void k_stats(
        const float* __restrict__ Hout, float* __restrict__ colsum,
        float* __restrict__ colsumsq) {
    __shared__ float ls[256], lq[256];
    int t = threadIdx.x;
    int c = t & 127, half = t >> 7;
    int rbase = blockIdx.x * 64;
    float sum = 0.f, sq = 0.f;
    #pragma unroll 4
    for (int i = 0; i < 32; ++i) {
        int r = rbase + half + i * 2;
        float v = Hout[(size_t)r * HD + c];
        sum += v;
        sq += v * v;
    }
    ls[t] = sum;
    lq[t] = sq;
    __syncthreads();
    if (t < 128) {
        sum = ls[t] + ls[t + 128];
        sq = lq[t] + lq[t + 128];
        atomicAdd(colsum + c, sum);
        atomicAdd(colsumsq + c, sq);
    }
}

// K6: out = tanh((h - mean) * rstd * gamma + beta), in place on d_out
__global__ __launch_bounds__(256) void k_apply(
        float* __restrict__ Hout, const float* __restrict__ colsum,
        const float* __restrict__ colsumsq, const float* __restrict__ gamma,
        const float* __restrict__ beta) {
    int idx = blockIdx.x * 256 + threadIdx.x;  // float4 index
    if (idx >= N_NODES * HD / 4) return;
    int c0 = (idx * 4) & 127;
    float4 h = ((const float4*)Hout)[idx];
    const float inv = 1.f / (float)N_NODES;
    float o[4];
    float hv[4] = {h.x, h.y, h.z, h.w};
    #pragma unroll
    for (int j = 0; j < 4; ++j) {
        int c = c0 + j;
        float mean = colsum[c] * inv;
        float var = colsumsq[c] * inv - mean * mean;
        float rstd = rsqrtf(var + BN_EPS);
        o[j] = tanhf((hv[j] - mean) * rstd * gamma[c] + beta[c]);
    }
    ((float4*)Hout)[idx] = make_float4(o[0], o[1], o[2], o[3]);
}

extern "C" void kernel_launch(void* const* d_in, const int* in_sizes, int n_in,
                              void* d_out, int out_size, void* d_ws, size_t ws_size,
                              hipStream_t stream) {
    const float* ent_emb  = (const float*)d_in[0];
    const float* rel_emb  = (const float*)d_in[1];
    const float* neigh_w  = (const float*)d_in[2];
    const float* bn_gamma = (const float*)d_in[3];
    const float* bn_beta  = (const float*)d_in[4];
    const int*   rel_id   = (const int*)d_in[5];
    const int*   dst      = (const int*)d_in[6];
    float* out = (float*)d_out;
    float* ws  = (float*)d_ws;

    unsigned* smax_u = (unsigned*)ws;            // [40000]
    float* denom   = ws + 40000;                 // [40000]
    float* s       = ws + 80000;                 // [640000]  (s, then ex in-place)
    float* neigh   = ws + 720000;                // [40000*128]
    float* colsum  = ws + 720000 + 5120000;      // [128]
    float* colsumsq = colsum + 128;              // [128]

    // zero all accumulators (mapped -inf == 0 for smax)
    hipMemsetAsync(d_ws, 0, (size_t)5840256 * 4, stream);

    k_edge_dot<<<N_EDGES / 8, 256, 0, stream>>>(rel_emb, ent_emb, rel_id, dst, s, smax_u);
    k_edge_exp<<<(N_EDGES + 255) / 256, 256, 0, stream>>>(dst, smax_u, s, denom);
    k_scatter<<<N_EDGES / 8, 256, 0, stream>>>(rel_emb, rel_id, dst, s, denom, neigh);
    k_gemm<<<N_NODES / 64, 256, 0, stream>>>(neigh, neigh_w, out);
    k_stats<<<N_NODES / 64, 256, 0, stream>>>(out, colsum, colsumsq);
    k_apply<<<(N_NODES * HD / 4 + 255) / 256, 256, 0, stream>>>(out, colsum, colsumsq, bn_gamma, bn_beta);
}

// Round 2
// 286.896 us; speedup vs baseline: 4.3997x; 4.3997x over previous
//
#include <hip/hip_runtime.h>

#define N_NODES 40000
#define N_EDGES 640000
#define HD 128
#define N_REL2 474
#define BN_EPS 1e-5f

// K1: histogram of edge destinations
__global__ __launch_bounds__(256) void k_hist(
        const int* __restrict__ dst, int* __restrict__ counts) {
    int e = blockIdx.x * 256 + threadIdx.x;
    if (e < N_EDGES) atomicAdd(counts + dst[e], 1);
}

// K2: single-block exclusive scan over 40000 counts -> row_off[40001], cursor
__global__ __launch_bounds__(1024) void k_scan(
        const int* __restrict__ counts, int* __restrict__ row_off,
        int* __restrict__ cursor) {
    __shared__ int part[1024];
    const int CH = 40;  // 1024*40 = 40960 >= 40000
    int t = threadIdx.x;
    int base = t * CH;
    int sum = 0;
    for (int i = 0; i < CH; ++i) {
        int idx = base + i;
        if (idx < N_NODES) sum += counts[idx];
    }
    part[t] = sum;
    __syncthreads();
    // Hillis-Steele inclusive scan
    for (int off = 1; off < 1024; off <<= 1) {
        int v = (t >= off) ? part[t - off] : 0;
        __syncthreads();
        part[t] += v;
        __syncthreads();
    }
    int run = (t == 0) ? 0 : part[t - 1];
    for (int i = 0; i < CH; ++i) {
        int idx = base + i;
        if (idx < N_NODES) {
            row_off[idx] = run;
            cursor[idx] = run;
            run += counts[idx];
        }
    }
    if (t == 1023) row_off[N_NODES] = part[1023];
}

// K3: scatter rel ids into CSR order (order within a node is irrelevant)
__global__ __launch_bounds__(256) void k_sortrel(
        const int* __restrict__ dst, const int* __restrict__ rel_id,
        int* __restrict__ cursor, int* __restrict__ sorted_rel) {
    int e = blockIdx.x * 256 + threadIdx.x;
    if (e < N_EDGES) {
        int p = atomicAdd(cursor + dst[e], 1);
        sorted_rel[p] = rel_id[e];
    }
}

// K4: RW = rel_emb @ neigh_w  (474 x 128 @ 128 x 128)
__global__ __launch_bounds__(128) void k_rw(
        const float* __restrict__ R, const float* __restrict__ W,
        float* __restrict__ RW) {
    __shared__ float row[HD];
    int r = blockIdx.x, c = threadIdx.x;
    row[c] = R[(size_t)r * HD + c];
    __syncthreads();
    float acc = 0.f;
    #pragma unroll 8
    for (int k = 0; k < HD; ++k) acc += row[k] * W[(size_t)k * HD + c];
    RW[(size_t)r * HD + c] = acc;
}

// K5: per-node online softmax + fused (softmax-weighted sum of RW rows)
//     h[n] = (sum_i exp(s_i - m) * RW[r_i]) / (sum_i exp(s_i - m))
__global__ __launch_bounds__(256) void k_node(
        const float* __restrict__ ent_emb, const float* __restrict__ R,
        const float* __restrict__ RW, const int* __restrict__ row_off,
        const int* __restrict__ sorted_rel, float* __restrict__ h) {
    int wave = threadIdx.x >> 6;
    int lane = threadIdx.x & 63;
    int n = blockIdx.x * 4 + wave;
    if (n >= N_NODES) return;
    int beg = row_off[n], end = row_off[n + 1];
    float2 ent = ((const float2*)(ent_emb + (size_t)n * HD))[lane];
    float m = -INFINITY, l = 0.f;
    float2 acc = make_float2(0.f, 0.f);
    for (int i = beg; i < end; ++i) {
        int r = sorted_rel[i];
        float2 rv = ((const float2*)(R + (size_t)r * HD))[lane];
        float dot = ent.x * rv.x + ent.y * rv.y;
        #pragma unroll
        for (int msk = 32; msk >= 1; msk >>= 1) dot += __shfl_xor(dot, msk, 64);
        float2 wv = ((const float2*)(RW + (size_t)r * HD))[lane];
        if (dot > m) {  // wave-uniform branch (dot identical across lanes)
            float scale = __expf(m - dot);  // first iter: exp(-inf)=0
            l *= scale;
            acc.x *= scale;
            acc.y *= scale;
            m = dot;
        }
        float p = __expf(dot - m);
        l += p;
        acc.x += p * wv.x;
        acc.y += p * wv.y;
    }
    float invl = (end > beg) ? 1.f / l : 0.f;
    ((float2*)(h + (size_t)n * HD))[lane] = make_float2(acc.x * invl, acc.y * invl);
}

// K6: per-column sum / sumsq over rows (block-partial -> global atomics)
__global__ __launch_bounds__(256) void k_stats(
        const float* __restrict__ Hout, float* __restrict__ colsum,
        float* __restrict__ colsumsq) {
    __shared__ float ls[256], lq[256];
    int t = threadIdx.x;
    int c = t & 127, half = t >> 7;
    int rbase = blockIdx.x * 64;
    float sum = 0.f, sq = 0.f;
    #pragma unroll 4
    for (int i = 0; i < 32; ++i) {
        int r = rbase + half + i * 2;
        float v = Hout[(size_t)r * HD + c];
        sum += v;
        sq += v * v;
    }
    ls[t] = sum;
    lq[t] = sq;
    __syncthreads();
    if (t < 128) {
        sum = ls[t] + ls[t + 128];
        sq = lq[t] + lq[t + 128];
        atomicAdd(colsum + c, sum);
        atomicAdd(colsumsq + c, sq);
    }
}

// K7: out = tanh((h - mean) * rstd * gamma + beta), in place on d_out
__global__ __launch_bounds__(256) void k_apply(
        float* __restrict__ Hout, const float* __restrict__ colsum,
        const float* __restrict__ colsumsq, const float* __restrict__ gamma,
        const float* __restrict__ beta) {
    int idx = blockIdx.x * 256 + threadIdx.x;  // float4 index
    if (idx >= N_NODES * HD / 4) return;
    int c0 = (idx * 4) & 127;
    float4 hv4 = ((const float4*)Hout)[idx];
    const float inv = 1.f / (float)N_NODES;
    float hv[4] = {hv4.x, hv4.y, hv4.z, hv4.w};
    float o[4];
    #pragma unroll
    for (int j = 0; j < 4; ++j) {
        int c = c0 + j;
        float mean = colsum[c] * inv;
        float var = colsumsq[c] * inv - mean * mean;
        float rstd = rsqrtf(var + BN_EPS);
        o[j] = tanhf((hv[j] - mean) * rstd * gamma[c] + beta[c]);
    }
    ((float4*)Hout)[idx] = make_float4(o[0], o[1], o[2], o[3]);
}

extern "C" void kernel_launch(void* const* d_in, const int* in_sizes, int n_in,
                              void* d_out, int out_size, void* d_ws, size_t ws_size,
                              hipStream_t stream) {
    const float* ent_emb  = (const float*)d_in[0];
    const float* rel_emb  = (const float*)d_in[1];
    const float* neigh_w  = (const float*)d_in[2];
    const float* bn_gamma = (const float*)d_in[3];
    const float* bn_beta  = (const float*)d_in[4];
    const int*   rel_id   = (const int*)d_in[5];
    const int*   dst      = (const int*)d_in[6];
    float* out = (float*)d_out;

    // workspace layout (4-byte units)
    int*   counts     = (int*)d_ws;                     // [40000]
    float* colsum     = (float*)d_ws + 40000;           // [128]
    float* colsumsq   = (float*)d_ws + 40128;           // [128]
    int*   row_off    = (int*)d_ws + 40256;             // [40001]
    int*   cursor     = (int*)d_ws + 80257;             // [40000]
    int*   sorted_rel = (int*)d_ws + 120257;            // [640000]
    float* RW         = (float*)d_ws + 760257;          // [474*128]

    // zero counts + colsum + colsumsq in one shot
    hipMemsetAsync(d_ws, 0, (size_t)(40000 + 256) * 4, stream);

    k_hist<<<(N_EDGES + 255) / 256, 256, 0, stream>>>(dst, counts);
    k_scan<<<1, 1024, 0, stream>>>(counts, row_off, cursor);
    k_sortrel<<<(N_EDGES + 255) / 256, 256, 0, stream>>>(dst, rel_id, cursor, sorted_rel);
    k_rw<<<N_REL2, 128, 0, stream>>>(rel_emb, neigh_w, RW);
    k_node<<<N_NODES / 4, 256, 0, stream>>>(ent_emb, rel_emb, RW, row_off, sorted_rel, out);
    k_stats<<<N_NODES / 64, 256, 0, stream>>>(out, colsum, colsumsq);
    k_apply<<<N_NODES * HD / 4 / 256, 256, 0, stream>>>(out, colsum, colsumsq, bn_gamma, bn_beta);
}

// Round 3
// 197.297 us; speedup vs baseline: 6.3977x; 1.4541x over previous
//
#include <hip/hip_runtime.h>

#define N_NODES 40000
#define N_EDGES 640000
#define HD 128
#define N_REL2 474
#define BN_EPS 1e-5f
#define NB_SCAN ((N_NODES + 255) / 256)  // 157 scan blocks

// K1: histogram of edge destinations
__global__ __launch_bounds__(256) void k_hist(
        const int* __restrict__ dst, int* __restrict__ counts) {
    int e = blockIdx.x * 256 + threadIdx.x;
    if (e < N_EDGES) atomicAdd(counts + dst[e], 1);
}

// K2a: per-block sum of 256 counts
__global__ __launch_bounds__(256) void k_scan_part(
        const int* __restrict__ counts, int* __restrict__ bsum) {
    __shared__ int ls[256];
    int t = threadIdx.x;
    int idx = blockIdx.x * 256 + t;
    ls[t] = (idx < N_NODES) ? counts[idx] : 0;
    __syncthreads();
    #pragma unroll
    for (int off = 128; off > 0; off >>= 1) {
        if (t < off) ls[t] += ls[t + off];
        __syncthreads();
    }
    if (t == 0) bsum[blockIdx.x] = ls[0];
}

// K2b: single tiny block — exclusive scan of NB_SCAN block sums in place
__global__ __launch_bounds__(256) void k_scan_top(int* __restrict__ bsum) {
    __shared__ int ls[256];
    int t = threadIdx.x;
    int v = (t < NB_SCAN) ? bsum[t] : 0;
    ls[t] = v;
    __syncthreads();
    #pragma unroll
    for (int off = 1; off < 256; off <<= 1) {
        int tmp = (t >= off) ? ls[t - off] : 0;
        __syncthreads();
        ls[t] += tmp;
        __syncthreads();
    }
    if (t < NB_SCAN) bsum[t] = ls[t] - v;  // exclusive
}

// K2c: per-block local exclusive scan + block offset -> row_off, cursor
__global__ __launch_bounds__(256) void k_scan_down(
        const int* __restrict__ counts, const int* __restrict__ bsum,
        int* __restrict__ row_off, int* __restrict__ cursor) {
    __shared__ int ls[256];
    int t = threadIdx.x;
    int idx = blockIdx.x * 256 + t;
    int v = (idx < N_NODES) ? counts[idx] : 0;
    ls[t] = v;
    __syncthreads();
    #pragma unroll
    for (int off = 1; off < 256; off <<= 1) {
        int tmp = (t >= off) ? ls[t - off] : 0;
        __syncthreads();
        ls[t] += tmp;
        __syncthreads();
    }
    int excl = ls[t] - v + bsum[blockIdx.x];
    if (idx < N_NODES) {
        row_off[idx] = excl;
        cursor[idx] = excl;
    }
    if (idx == N_NODES) row_off[N_NODES] = N_EDGES;
}

// K3: scatter rel ids into CSR order (order within a node is irrelevant)
__global__ __launch_bounds__(256) void k_sortrel(
        const int* __restrict__ dst, const int* __restrict__ rel_id,
        int* __restrict__ cursor, int* __restrict__ sorted_rel) {
    int e = blockIdx.x * 256 + threadIdx.x;
    if (e < N_EDGES) {
        int p = atomicAdd(cursor + dst[e], 1);
        sorted_rel[p] = rel_id[e];
    }
}

// K4: RW = rel_emb @ neigh_w  (474 x 128 @ 128 x 128)
__global__ __launch_bounds__(128) void k_rw(
        const float* __restrict__ R, const float* __restrict__ W,
        float* __restrict__ RW) {
    __shared__ float row[HD];
    int r = blockIdx.x, c = threadIdx.x;
    row[c] = R[(size_t)r * HD + c];
    __syncthreads();
    float acc = 0.f;
    #pragma unroll 8
    for (int k = 0; k < HD; ++k) acc += row[k] * W[(size_t)k * HD + c];
    RW[(size_t)r * HD + c] = acc;
}

// K5: per-node online softmax + fused (softmax-weighted sum of RW rows)
__global__ __launch_bounds__(256) void k_node(
        const float* __restrict__ ent_emb, const float* __restrict__ R,
        const float* __restrict__ RW, const int* __restrict__ row_off,
        const int* __restrict__ sorted_rel, float* __restrict__ h) {
    int wave = threadIdx.x >> 6;
    int lane = threadIdx.x & 63;
    int n = blockIdx.x * 4 + wave;
    if (n >= N_NODES) return;
    int beg = row_off[n], end = row_off[n + 1];
    float2 ent = ((const float2*)(ent_emb + (size_t)n * HD))[lane];
    float m = -INFINITY, l = 0.f;
    float2 acc = make_float2(0.f, 0.f);
    for (int i = beg; i < end; ++i) {
        int r = sorted_rel[i];
        float2 rv = ((const float2*)(R + (size_t)r * HD))[lane];
        float dot = ent.x * rv.x + ent.y * rv.y;
        #pragma unroll
        for (int msk = 32; msk >= 1; msk >>= 1) dot += __shfl_xor(dot, msk, 64);
        float2 wv = ((const float2*)(RW + (size_t)r * HD))[lane];
        if (dot > m) {  // wave-uniform branch (dot identical across lanes)
            float scale = __expf(m - dot);  // first iter: exp(-inf)=0
            l *= scale;
            acc.x *= scale;
            acc.y *= scale;
            m = dot;
        }
        float p = __expf(dot - m);
        l += p;
        acc.x += p * wv.x;
        acc.y += p * wv.y;
    }
    float invl = (end > beg) ? 1.f / l : 0.f;
    ((float2*)(h + (size_t)n * HD))[lane] = make_float2(acc.x * invl, acc.y * invl);
}

// K6: per-column sum / sumsq over rows (block-partial -> global atomics)
__global__ __launch_bounds__(256) void k_stats(
        const float* __restrict__ Hout, float* __restrict__ colsum,
        float* __restrict__ colsumsq) {
    __shared__ float ls[256], lq[256];
    int t = threadIdx.x;
    int c = t & 127, half = t >> 7;
    int rbase = blockIdx.x * 64;
    float sum = 0.f, sq = 0.f;
    #pragma unroll 4
    for (int i = 0; i < 32; ++i) {
        int r = rbase + half + i * 2;
        float v = Hout[(size_t)r * HD + c];
        sum += v;
        sq += v * v;
    }
    ls[t] = sum;
    lq[t] = sq;
    __syncthreads();
    if (t < 128) {
        sum = ls[t] + ls[t + 128];
        sq = lq[t] + lq[t + 128];
        atomicAdd(colsum + c, sum);
        atomicAdd(colsumsq + c, sq);
    }
}

// K7: out = tanh((h - mean) * rstd * gamma + beta), in place on d_out
__global__ __launch_bounds__(256) void k_apply(
        float* __restrict__ Hout, const float* __restrict__ colsum,
        const float* __restrict__ colsumsq, const float* __restrict__ gamma,
        const float* __restrict__ beta) {
    int idx = blockIdx.x * 256 + threadIdx.x;  // float4 index
    if (idx >= N_NODES * HD / 4) return;
    int c0 = (idx * 4) & 127;
    float4 hv4 = ((const float4*)Hout)[idx];
    const float inv = 1.f / (float)N_NODES;
    float hv[4] = {hv4.x, hv4.y, hv4.z, hv4.w};
    float o[4];
    #pragma unroll
    for (int j = 0; j < 4; ++j) {
        int c = c0 + j;
        float mean = colsum[c] * inv;
        float var = colsumsq[c] * inv - mean * mean;
        float rstd = rsqrtf(var + BN_EPS);
        o[j] = tanhf((hv[j] - mean) * rstd * gamma[c] + beta[c]);
    }
    ((float4*)Hout)[idx] = make_float4(o[0], o[1], o[2], o[3]);
}

extern "C" void kernel_launch(void* const* d_in, const int* in_sizes, int n_in,
                              void* d_out, int out_size, void* d_ws, size_t ws_size,
                              hipStream_t stream) {
    const float* ent_emb  = (const float*)d_in[0];
    const float* rel_emb  = (const float*)d_in[1];
    const float* neigh_w  = (const float*)d_in[2];
    const float* bn_gamma = (const float*)d_in[3];
    const float* bn_beta  = (const float*)d_in[4];
    const int*   rel_id   = (const int*)d_in[5];
    const int*   dst      = (const int*)d_in[6];
    float* out = (float*)d_out;

    // workspace layout (4-byte units)
    int*   counts     = (int*)d_ws;                     // [40000]
    float* colsum     = (float*)d_ws + 40000;           // [128]
    float* colsumsq   = (float*)d_ws + 40128;           // [128]
    int*   row_off    = (int*)d_ws + 40256;             // [40001]
    int*   cursor     = (int*)d_ws + 80257;             // [40000]
    int*   sorted_rel = (int*)d_ws + 120257;            // [640000]
    float* RW         = (float*)d_ws + 760257;          // [474*128]
    int*   bsum       = (int*)d_ws + 760257 + N_REL2 * HD;  // [NB_SCAN]

    // zero counts + colsum + colsumsq in one shot
    hipMemsetAsync(d_ws, 0, (size_t)(40000 + 256) * 4, stream);

    k_hist<<<(N_EDGES + 255) / 256, 256, 0, stream>>>(dst, counts);
    k_scan_part<<<NB_SCAN, 256, 0, stream>>>(counts, bsum);
    k_scan_top<<<1, 256, 0, stream>>>(bsum);
    k_scan_down<<<NB_SCAN, 256, 0, stream>>>(counts, bsum, row_off, cursor);
    k_sortrel<<<(N_EDGES + 255) / 256, 256, 0, stream>>>(dst, rel_id, cursor, sorted_rel);
    k_rw<<<N_REL2, 128, 0, stream>>>(rel_emb, neigh_w, RW);
    k_node<<<N_NODES / 4, 256, 0, stream>>>(ent_emb, rel_emb, RW, row_off, sorted_rel, out);
    k_stats<<<N_NODES / 64, 256, 0, stream>>>(out, colsum, colsumsq);
    k_apply<<<N_NODES * HD / 4 / 256, 256, 0, stream>>>(out, colsum, colsumsq, bn_gamma, bn_beta);
}